// Round 2
// baseline (163.730 us; speedup 1.0000x reference)
//
#include <hip/hip_runtime.h>
#include <hip/hip_fp16.h>

// SkipGram negative-sampling loss. B=32768, K=16, D=128, fp32 inputs.
// Round 9: Round-8 quarter-wave gather geometry, compile fix:
//   __builtin_amdgcn_cvt_pk_f32_fp8's word-select must be a literal at the
//   call site -> dec2 is now template<bool HI>.
// Structure:
//   - Each 16-lane quarter owns one row slice of 8 dims (uint2 = 8 B/lane),
//     so ONE VMEM instruction gathers FOUR negative rows (vs 4 insts before).
//   - Per-wave VMEM: 19 -> 7 (2x float4 word, 1x uint2 pos, 4x uint2 neg).
//   - Butterfly: 4-value/2-step tree + 2 shuffles (was 16-value/4-step + 6).
// Same cache lines touched as R7 (traffic unchanged); attacks VMEM issue
// count and the dependent shuffle tail (latency/issue hypothesis).

constexpr int Bn = 32768;
constexpr int Kn = 16;
constexpr int WPB = 4;                    // waves per block (256 threads)
constexpr int NBLK = Bn / WPB;            // 8192 blocks
constexpr int VOCAB = 100000;
constexpr int DIM = 128;
constexpr size_t CONV_OFF = 65536;        // byte offset of fp8 table in d_ws
constexpr float SCALE = 256.0f;           // fp32 -> e4m3 pre-scale
constexpr float INV_SCALE = 1.0f / 256.0f;

typedef float f32x2 __attribute__((ext_vector_type(2)));

__device__ __forceinline__ float log_sigmoid_fast(float x) {
  // min(x,0) - log(1 + exp(-|x|)); log arg in (1,2] -> hw v_log_f32 accurate
  return fminf(x, 0.0f) - __logf(1.0f + __expf(-fabsf(x)));
}

// Multi-value butterfly step: C live values per lane -> C/2, partner mask M.
template<int M, int C>
__device__ __forceinline__ void tree_step(float* v, int lane) {
  const bool hi = (lane & M) != 0;
  const int H = C / 2;
#pragma unroll
  for (int j = 0; j < H; ++j) {
    float send = hi ? v[j] : v[j + H];
    float keep = hi ? v[j + H] : v[j];
    v[j] = keep + __shfl_xor(send, M, 64);
  }
}

// Decode two e4m3 bytes (low/high word of a uint) -> float2, hw converter.
// HI must be a compile-time constant (builtin requirement).
template<bool HI>
__device__ __forceinline__ f32x2 dec2(unsigned int w) {
  return __builtin_amdgcn_cvt_pk_f32_fp8((int)w, HI);
}

// fp32 -> e4m3 table conversion via hw converter, 4 values/thread, streaming.
__global__ __launch_bounds__(256) void convert_con(
    const float4* __restrict__ in, unsigned int* __restrict__ out, int n4)
{
  int i = blockIdx.x * 256 + threadIdx.x;
  if (i >= n4) return;
  float4 v = in[i];
  int w = 0;
  w = __builtin_amdgcn_cvt_pk_fp8_f32(v.x * SCALE, v.y * SCALE, w, false);
  w = __builtin_amdgcn_cvt_pk_fp8_f32(v.z * SCALE, v.w * SCALE, w, true);
  out[i] = (unsigned int)w;
}

__global__ __launch_bounds__(256) void skipgram_main(
    const int* __restrict__ centrals,
    const int* __restrict__ pos_ctx,
    const int* __restrict__ neg_ctx,
    const float* __restrict__ word_emb,
    const unsigned short* __restrict__ con8,   // e4m3 table, 64 ushort/row
    float* __restrict__ block_sums)
{
  const int lane = threadIdx.x & 63;
  int b = blockIdx.x * WPB + (threadIdx.x >> 6);
  b = __builtin_amdgcn_readfirstlane(b);    // wave-uniform -> s_load path

  const int m = lane & 15;                  // 8-dim slice id within a row
  const int q = lane >> 4;                  // quarter-wave id (0..3)

  const int cw = centrals[b];
  const int pc = pos_ctx[b];
  int ni[Kn];
#pragma unroll
  for (int k = 0; k < Kn; ++k) ni[k] = neg_ctx[b * Kn + k];

  // Quarter q of gather-instruction j handles neg row ni[4j+q].
  const bool q1 = (q & 1) != 0;
  const bool q2 = (q & 2) != 0;
  int rowj[4];
#pragma unroll
  for (int j = 0; j < 4; ++j) {
    int t0 = q1 ? ni[4 * j + 1] : ni[4 * j + 0];
    int t1 = q1 ? ni[4 * j + 3] : ni[4 * j + 2];
    rowj[j] = q2 ? t1 : t0;
  }

  // Issue all 7 row gathers back-to-back.
  // word: lane needs fp32 dims [8m, 8m+8) -> two float4 (quarter-replicated,
  // L1-served: 512 B unique per inst). con rows: uint2 = 8 fp8 vals/lane.
  const float4* __restrict__ Wr =
      reinterpret_cast<const float4*>(word_emb + (size_t)cw * DIM + m * 8);
  const float4 wa = Wr[0];
  const float4 wb = Wr[1];
  const uint2 pv = *reinterpret_cast<const uint2*>(con8 + (size_t)pc * 64 + m * 4);
  uint2 nv[4];
#pragma unroll
  for (int j = 0; j < 4; ++j)
    nv[j] = *reinterpret_cast<const uint2*>(con8 + (size_t)rowj[j] * 64 + m * 4);

  // Per-lane partial dot over its 8-dim slice, 4 rows in flight (ILP).
  float v[4];
#pragma unroll
  for (int j = 0; j < 4; ++j) {
    const f32x2 a0 = dec2<false>(nv[j].x);
    const f32x2 a1 = dec2<true >(nv[j].x);
    const f32x2 a2 = dec2<false>(nv[j].y);
    const f32x2 a3 = dec2<true >(nv[j].y);
    v[j] = fmaf(wa.x, a0.x,
           fmaf(wa.y, a0.y,
           fmaf(wa.z, a1.x,
           fmaf(wa.w, a1.y,
           fmaf(wb.x, a2.x,
           fmaf(wb.y, a2.y,
           fmaf(wb.z, a3.x, wb.w * a3.y)))))));
  }

  // 4 partials -> one score per lane (2 tree steps), then close the sum
  // across the four 4-lane quads of each quarter (2 shuffles).
  tree_step<1, 4>(v, lane);
  tree_step<2, 2>(v, lane);
  float s = v[0];
  s += __shfl_xor(s, 4, 64);
  s += __shfl_xor(s, 8, 64);
  s *= INV_SCALE;                          // undo e4m3 pre-scale

  // 16 distinct scores live at (lane&3) x quarter; sum their log-sigmoids.
  float nls = log_sigmoid_fast(-s);
  nls += __shfl_xor(nls, 1, 64);
  nls += __shfl_xor(nls, 2, 64);
  nls += __shfl_xor(nls, 16, 64);
  nls += __shfl_xor(nls, 32, 64);          // neg_loss total (all lanes)

  // Positive score: per-lane 8-dim partial (quarters replicate), 4 shuffles.
  const f32x2 c0 = dec2<false>(pv.x);
  const f32x2 c1 = dec2<true >(pv.x);
  const f32x2 c2 = dec2<false>(pv.y);
  const f32x2 c3 = dec2<true >(pv.y);
  float pp = fmaf(wa.x, c0.x,
             fmaf(wa.y, c0.y,
             fmaf(wa.z, c1.x,
             fmaf(wa.w, c1.y,
             fmaf(wb.x, c2.x,
             fmaf(wb.y, c2.y,
             fmaf(wb.z, c3.x, wb.w * c3.y)))))));
  pp += __shfl_xor(pp, 1, 64);
  pp += __shfl_xor(pp, 2, 64);
  pp += __shfl_xor(pp, 4, 64);
  pp += __shfl_xor(pp, 8, 64);
  pp *= INV_SCALE;                         // undo e4m3 pre-scale

  const float acc = log_sigmoid_fast(pp) + nls;

  __shared__ float smem[WPB];
  if (lane == 0) smem[threadIdx.x >> 6] = acc;
  __syncthreads();
  if (threadIdx.x == 0)
    block_sums[blockIdx.x] = (smem[0] + smem[1]) + (smem[2] + smem[3]);
}

__global__ __launch_bounds__(256) void skipgram_reduce(
    const float* __restrict__ block_sums, float* __restrict__ out)
{
  float s = 0.0f;
#pragma unroll
  for (int i = 0; i < NBLK / 256; ++i) s += block_sums[i * 256 + threadIdx.x];
  s += __shfl_xor(s,  1, 64);
  s += __shfl_xor(s,  2, 64);
  s += __shfl_xor(s,  4, 64);
  s += __shfl_xor(s,  8, 64);
  s += __shfl_xor(s, 16, 64);
  s += __shfl_xor(s, 32, 64);
  __shared__ float smem[4];
  const int lane = threadIdx.x & 63;
  if (lane == 0) smem[threadIdx.x >> 6] = s;
  __syncthreads();
  if (threadIdx.x == 0) {
    float t = (smem[0] + smem[1]) + (smem[2] + smem[3]);
    out[0] = -t * (1.0f / (float)Bn);     // loss = -mean(pos_loss + neg_loss)
  }
}

extern "C" void kernel_launch(void* const* d_in, const int* in_sizes, int n_in,
                              void* d_out, int out_size, void* d_ws, size_t ws_size,
                              hipStream_t stream) {
  const int*   centrals = (const int*)d_in[0];
  const int*   pos_ctx  = (const int*)d_in[1];
  const int*   neg_ctx  = (const int*)d_in[2];
  const float* word_emb = (const float*)d_in[3];
  const float* con_emb  = (const float*)d_in[4];
  float*       out      = (float*)d_out;

  float*        block_sums = (float*)d_ws;                     // 32 KB
  unsigned int* con_fp8 = (unsigned int*)((char*)d_ws + CONV_OFF); // 12.8 MB

  // 1) fp32 -> e4m3 conversion (streaming, 64 MB traffic, hw cvt).
  const int n4 = VOCAB * DIM / 4;                              // 3.2M float4
  convert_con<<<(n4 + 255) / 256, 256, 0, stream>>>(
      (const float4*)con_emb, con_fp8, n4);

  // 2) gathers + dots + log-sigmoid -> per-block partials.
  skipgram_main<<<NBLK, 256, 0, stream>>>(centrals, pos_ctx, neg_ctx,
                                          word_emb,
                                          (const unsigned short*)con_fp8,
                                          block_sums);

  // 3) final mean.
  skipgram_reduce<<<1, 256, 0, stream>>>(block_sums, out);
}

// Round 3
// 137.870 us; speedup vs baseline: 1.1876x; 1.1876x over previous
//
#include <hip/hip_runtime.h>
#include <hip/hip_fp16.h>

// SkipGram negative-sampling loss. B=32768, K=16, D=128, fp32 inputs.
// Round 10: REVERT R9's quarter-wave geometry (measured 2x slower: divergent
// 4-row uint2 gathers serialize in the TA; full-wave contiguous gathers win).
// Back to R7 geometry + NEW: two b per wave.
//   - 38 row gathers issued back-to-back per wave (was 19): doubles
//     memory-level parallelism per wave to attack the measured latency-bound
//     regime (main: 800 GB/s = 10% HBM, VALUBusy 20%, occupancy 55%).
//   - The two reduction trees are independent; stages interleaved at source
//     level so DS-shuffle latency of tree0 hides under tree1 and vice versa.

constexpr int Bn = 32768;
constexpr int Kn = 16;
constexpr int WPB = 4;                    // waves per block (256 threads)
constexpr int BPW = 2;                    // b's per wave
constexpr int NBLK = Bn / (WPB * BPW);    // 4096 blocks
constexpr int VOCAB = 100000;
constexpr int DIM = 128;
constexpr size_t CONV_OFF = 65536;        // byte offset of fp8 table in d_ws
constexpr float SCALE = 256.0f;           // fp32 -> e4m3 pre-scale
constexpr float INV_SCALE = 1.0f / 256.0f;

typedef float f32x2 __attribute__((ext_vector_type(2)));

__device__ __forceinline__ float log_sigmoid_fast(float x) {
  // min(x,0) - log(1 + exp(-|x|)); log arg in (1,2] -> hw v_log_f32 accurate
  return fminf(x, 0.0f) - __logf(1.0f + __expf(-fabsf(x)));
}

// Multi-value butterfly step: C live values per lane -> C/2, partner mask M.
template<int M, int C>
__device__ __forceinline__ void tree_step(float* v, int lane) {
  const bool hi = (lane & M) != 0;
  const int H = C / 2;
#pragma unroll
  for (int j = 0; j < H; ++j) {
    float send = hi ? v[j] : v[j + H];
    float keep = hi ? v[j + H] : v[j];
    v[j] = keep + __shfl_xor(send, M, 64);
  }
}

// Decode two e4m3 bytes (packed in a ushort) -> float2, via hw converter.
__device__ __forceinline__ f32x2 dec2_fp8(unsigned short t) {
  return __builtin_amdgcn_cvt_pk_f32_fp8((int)(unsigned int)t, false);
}

// fp32 -> e4m3 table conversion via hw converter, 4 values/thread, streaming.
__global__ __launch_bounds__(256) void convert_con(
    const float4* __restrict__ in, unsigned int* __restrict__ out, int n4)
{
  int i = blockIdx.x * 256 + threadIdx.x;
  if (i >= n4) return;
  float4 v = in[i];
  int w = 0;
  w = __builtin_amdgcn_cvt_pk_fp8_f32(v.x * SCALE, v.y * SCALE, w, false);
  w = __builtin_amdgcn_cvt_pk_fp8_f32(v.z * SCALE, v.w * SCALE, w, true);
  out[i] = (unsigned int)w;
}

__global__ __launch_bounds__(256) void skipgram_main(
    const int* __restrict__ centrals,
    const int* __restrict__ pos_ctx,
    const int* __restrict__ neg_ctx,
    const float* __restrict__ word_emb,
    const unsigned short* __restrict__ con8,   // e4m3 table, 64 ushort/row
    float* __restrict__ block_sums)
{
  const int lane = threadIdx.x & 63;
  int b0 = (blockIdx.x * WPB + (threadIdx.x >> 6)) * BPW;
  b0 = __builtin_amdgcn_readfirstlane(b0);  // wave-uniform -> s_load path

  const float2* __restrict__ W = reinterpret_cast<const float2*>(word_emb);

  // Scalar index loads for both b (wave-uniform addresses -> s_load).
  const int cw0 = centrals[b0],    cw1 = centrals[b0 + 1];
  const int pc0 = pos_ctx[b0],     pc1 = pos_ctx[b0 + 1];
  int ni0[Kn], ni1[Kn];
#pragma unroll
  for (int k = 0; k < Kn; ++k) {
    ni0[k] = neg_ctx[b0 * Kn + k];
    ni1[k] = neg_ctx[(b0 + 1) * Kn + k];
  }

  // Issue all 38 row gathers back-to-back (MLP). Full-wave contiguous:
  // word rows 512 B fp32 (float2/lane), con rows 128 B fp8 (ushort/lane).
  const float2 wv0 = W[(size_t)cw0 * 64 + lane];
  const float2 wv1 = W[(size_t)cw1 * 64 + lane];
  const unsigned short cvb0 = con8[(size_t)pc0 * 64 + lane];
  const unsigned short cvb1 = con8[(size_t)pc1 * 64 + lane];
  unsigned short nvb0[Kn], nvb1[Kn];
#pragma unroll
  for (int k = 0; k < Kn; ++k) nvb0[k] = con8[(size_t)ni0[k] * 64 + lane];
#pragma unroll
  for (int k = 0; k < Kn; ++k) nvb1[k] = con8[(size_t)ni1[k] * 64 + lane];

  // Per-lane partial dots for both b (independent chains, ILP).
  float v0[Kn], v1[Kn];
#pragma unroll
  for (int k = 0; k < Kn; ++k) {
    const f32x2 n0 = dec2_fp8(nvb0[k]);
    v0[k] = fmaf(wv0.x, n0.x, wv0.y * n0.y);
    const f32x2 n1 = dec2_fp8(nvb1[k]);
    v1[k] = fmaf(wv1.x, n1.x, wv1.y * n1.y);
  }

  // Two independent butterfly trees, stage-interleaved for DS-latency ILP.
  tree_step<1, 16>(v0, lane);  tree_step<1, 16>(v1, lane);
  tree_step<2,  8>(v0, lane);  tree_step<2,  8>(v1, lane);
  tree_step<4,  4>(v0, lane);  tree_step<4,  4>(v1, lane);
  tree_step<8,  2>(v0, lane);  tree_step<8,  2>(v1, lane);
  float s0 = v0[0], s1 = v1[0];
  s0 += __shfl_xor(s0, 16, 64);  s1 += __shfl_xor(s1, 16, 64);
  s0 += __shfl_xor(s0, 32, 64);  s1 += __shfl_xor(s1, 32, 64);
  s0 *= INV_SCALE;               s1 *= INV_SCALE;

  // Sum log-sigmoids of the 16 distinct scores per b (interleaved chains).
  float nls0 = log_sigmoid_fast(-s0);
  float nls1 = log_sigmoid_fast(-s1);
  nls0 += __shfl_xor(nls0, 1, 64);  nls1 += __shfl_xor(nls1, 1, 64);
  nls0 += __shfl_xor(nls0, 2, 64);  nls1 += __shfl_xor(nls1, 2, 64);
  nls0 += __shfl_xor(nls0, 4, 64);  nls1 += __shfl_xor(nls1, 4, 64);
  nls0 += __shfl_xor(nls0, 8, 64);  nls1 += __shfl_xor(nls1, 8, 64);

  // Positive scores (interleaved chains).
  const f32x2 cf0 = dec2_fp8(cvb0);
  const f32x2 cf1 = dec2_fp8(cvb1);
  float pp0 = fmaf(wv0.x, cf0.x, wv0.y * cf0.y);
  float pp1 = fmaf(wv1.x, cf1.x, wv1.y * cf1.y);
  pp0 += __shfl_xor(pp0,  1, 64);  pp1 += __shfl_xor(pp1,  1, 64);
  pp0 += __shfl_xor(pp0,  2, 64);  pp1 += __shfl_xor(pp1,  2, 64);
  pp0 += __shfl_xor(pp0,  4, 64);  pp1 += __shfl_xor(pp1,  4, 64);
  pp0 += __shfl_xor(pp0,  8, 64);  pp1 += __shfl_xor(pp1,  8, 64);
  pp0 += __shfl_xor(pp0, 16, 64);  pp1 += __shfl_xor(pp1, 16, 64);
  pp0 += __shfl_xor(pp0, 32, 64);  pp1 += __shfl_xor(pp1, 32, 64);
  pp0 *= INV_SCALE;                pp1 *= INV_SCALE;

  const float acc = (log_sigmoid_fast(pp0) + nls0)
                  + (log_sigmoid_fast(pp1) + nls1);

  __shared__ float smem[WPB];
  if (lane == 0) smem[threadIdx.x >> 6] = acc;
  __syncthreads();
  if (threadIdx.x == 0)
    block_sums[blockIdx.x] = (smem[0] + smem[1]) + (smem[2] + smem[3]);
}

__global__ __launch_bounds__(256) void skipgram_reduce(
    const float* __restrict__ block_sums, float* __restrict__ out)
{
  float s = 0.0f;
#pragma unroll
  for (int i = 0; i < NBLK / 256; ++i) s += block_sums[i * 256 + threadIdx.x];
  s += __shfl_xor(s,  1, 64);
  s += __shfl_xor(s,  2, 64);
  s += __shfl_xor(s,  4, 64);
  s += __shfl_xor(s,  8, 64);
  s += __shfl_xor(s, 16, 64);
  s += __shfl_xor(s, 32, 64);
  __shared__ float smem[4];
  const int lane = threadIdx.x & 63;
  if (lane == 0) smem[threadIdx.x >> 6] = s;
  __syncthreads();
  if (threadIdx.x == 0) {
    float t = (smem[0] + smem[1]) + (smem[2] + smem[3]);
    out[0] = -t * (1.0f / (float)Bn);     // loss = -mean(pos_loss + neg_loss)
  }
}

extern "C" void kernel_launch(void* const* d_in, const int* in_sizes, int n_in,
                              void* d_out, int out_size, void* d_ws, size_t ws_size,
                              hipStream_t stream) {
  const int*   centrals = (const int*)d_in[0];
  const int*   pos_ctx  = (const int*)d_in[1];
  const int*   neg_ctx  = (const int*)d_in[2];
  const float* word_emb = (const float*)d_in[3];
  const float* con_emb  = (const float*)d_in[4];
  float*       out      = (float*)d_out;

  float*        block_sums = (float*)d_ws;                     // 16 KB
  unsigned int* con_fp8 = (unsigned int*)((char*)d_ws + CONV_OFF); // 12.8 MB

  // 1) fp32 -> e4m3 conversion (streaming, 64 MB traffic, hw cvt).
  const int n4 = VOCAB * DIM / 4;                              // 3.2M float4
  convert_con<<<(n4 + 255) / 256, 256, 0, stream>>>(
      (const float4*)con_emb, con_fp8, n4);

  // 2) gathers + dots + log-sigmoid -> per-block partials.
  skipgram_main<<<NBLK, 256, 0, stream>>>(centrals, pos_ctx, neg_ctx,
                                          word_emb,
                                          (const unsigned short*)con_fp8,
                                          block_sums);

  // 3) final mean.
  skipgram_reduce<<<1, 256, 0, stream>>>(block_sums, out);
}